// Round 16
// baseline (4672.789 us; speedup 1.0000x reference)
//
#include <hip/hip_runtime.h>

// ============================================================================
// NMT seq2seq forward — Round 16: R15 base (best: 4191 us) + attnSB hop folded
// into S0 via gemm_att (6 -> 5 hops/step; R8's fold, now isolated).
// E=512 H=1024 L=4 V=32000 B=64 SS=48 TT=48 (dec steps = 47)
// ============================================================================

typedef __attribute__((ext_vector_type(8))) short bf16x8;
typedef __attribute__((ext_vector_type(4))) float f32x4;

#define SMEM_BYTES 32768  // gemm core: 4 swizzled 8KB tiles
#define SMEM_A     65536  // dec_stage (gemm_att path: 4 x 16KB slots)
#define SMEM_RO    49152  // readout: 2 slots x (2 A-tiles + B-tile) x 8KB

#define NMT_SYNC_LIGHT()                                   \
  do {                                                     \
    asm volatile("s_waitcnt lgkmcnt(0)" ::: "memory");     \
    __builtin_amdgcn_s_barrier();                          \
    __builtin_amdgcn_sched_barrier(0);                     \
  } while (0)

__device__ __forceinline__ float bf2f(ushort u) {
  union { uint i; float f; } v; v.i = ((uint)u) << 16; return v.f;
}
__device__ __forceinline__ ushort f2bf(float x) {
  union { float f; uint i; } v; v.f = x;
  uint r = (v.i + 0x7fffu + ((v.i >> 16) & 1u)) >> 16;
  return (ushort)r;
}
__device__ __forceinline__ uint pack2(float x, float y) {
  return (uint)f2bf(x) | ((uint)f2bf(y) << 16);
}
__device__ __forceinline__ float sigm(float x) {
  return __fdividef(1.f, 1.f + __expf(-x));
}
__device__ __forceinline__ float tanhf_fast(float x) {
  const float e = __expf(2.f * x);
  return 1.f - __fdividef(2.f, e + 1.f);
}

// ---------------------------------------------------------------------------
// Pipelined swizzled GEMM core (R7): acc += A[m0..+64,:K] @ W[n0..+64,:K]^T
// ---------------------------------------------------------------------------
__device__ __forceinline__ void gemm_term(
    const ushort* __restrict__ A, int lda,
    const ushort* __restrict__ W, int ldw,
    int K, int m0, int n0,
    f32x4 acc[4], char* s)
{
  char* sA0 = s;
  char* sB0 = s + 8192;
  char* sA1 = s + 16384;
  char* sB1 = s + 24576;
  const int tid = threadIdx.x;
  const int lane = tid & 63;
  const int w = tid >> 6;
  const int r0 = tid >> 3;
  const int cge = (tid & 7) << 3;
  const ushort* Arow0 = A + (size_t)(m0 + r0) * lda + cge;
  const ushort* Arow1 = A + (size_t)(m0 + r0 + 32) * lda + cge;
  const ushort* Wrow0 = W + (size_t)(n0 + r0) * ldw + cge;
  const ushort* Wrow1 = W + (size_t)(n0 + r0 + 32) * ldw + cge;
  const int so0 = r0 * 128 + (((tid & 7) << 4) ^ ((r0 & 7) << 4));
  const int so1 = so0 + 4096;

  uint4 a0 = *reinterpret_cast<const uint4*>(Arow0);
  uint4 a1 = *reinterpret_cast<const uint4*>(Arow1);
  uint4 b0 = *reinterpret_cast<const uint4*>(Wrow0);
  uint4 b1 = *reinterpret_cast<const uint4*>(Wrow1);
  *reinterpret_cast<uint4*>(sA0 + so0) = a0;
  *reinterpret_cast<uint4*>(sA0 + so1) = a1;
  *reinterpret_cast<uint4*>(sB0 + so0) = b0;
  *reinterpret_cast<uint4*>(sB0 + so1) = b1;
  if (K > 64) {
    a0 = *reinterpret_cast<const uint4*>(Arow0 + 64);
    a1 = *reinterpret_cast<const uint4*>(Arow1 + 64);
    b0 = *reinterpret_cast<const uint4*>(Wrow0 + 64);
    b1 = *reinterpret_cast<const uint4*>(Wrow1 + 64);
  }
  const int axor = (lane & 7) << 4;
  const int arow = (w * 16 + (lane & 15)) * 128;
  const int brow = (lane & 15) * 128;
  const int kb0 = (lane >> 4) << 4;
  for (int kt = 0; kt < K; kt += 64) {
    char* cA = (kt & 64) ? sA1 : sA0;
    char* cB = (kt & 64) ? sB1 : sB0;
    char* nA = (kt & 64) ? sA0 : sA1;
    char* nB = (kt & 64) ? sB0 : sB1;
    __syncthreads();
    if (kt + 64 < K) {
      *reinterpret_cast<uint4*>(nA + so0) = a0;
      *reinterpret_cast<uint4*>(nA + so1) = a1;
      *reinterpret_cast<uint4*>(nB + so0) = b0;
      *reinterpret_cast<uint4*>(nB + so1) = b1;
      if (kt + 128 < K) {
        a0 = *reinterpret_cast<const uint4*>(Arow0 + kt + 128);
        a1 = *reinterpret_cast<const uint4*>(Arow1 + kt + 128);
        b0 = *reinterpret_cast<const uint4*>(Wrow0 + kt + 128);
        b1 = *reinterpret_cast<const uint4*>(Wrow1 + kt + 128);
      }
    }
#pragma unroll
    for (int ks = 0; ks < 2; ++ks) {
      const int kb = ks * 64 + kb0;
      bf16x8 af = *reinterpret_cast<const bf16x8*>(cA + arow + (kb ^ axor));
#pragma unroll
      for (int nf = 0; nf < 4; ++nf) {
        bf16x8 bfr = *reinterpret_cast<const bf16x8*>(
            cB + nf * 2048 + brow + (kb ^ axor));
        acc[nf] = __builtin_amdgcn_mfma_f32_16x16x32_bf16(af, bfr, acc[nf], 0, 0, 0);
      }
    }
  }
  __syncthreads();
}

// ---------------------------------------------------------------------------
// gemm_att: BK=128 double-buffer, A staged on the fly as tanh(H+C2) -> bf16.
// H, C2: 64 x 1024 f32 row-major. K = 1024 fixed. Needs 64KB LDS.
// ---------------------------------------------------------------------------
__device__ __forceinline__ void att_loadf(
    const float* H0, const float* H1, const float* C0, const float* C1,
    int kt, float4* fh, float4* fc)
{
#pragma unroll
  for (int q = 0; q < 8; ++q) {
    const int rh = q >> 2, sub = (q >> 1) & 1, vq = q & 1;
    const float* hp_ = rh ? H1 : H0;
    const float* cp_ = rh ? C1 : C0;
    fh[q] = *reinterpret_cast<const float4*>(hp_ + kt + sub * 64 + vq * 4);
    fc[q] = *reinterpret_cast<const float4*>(cp_ + kt + sub * 64 + vq * 4);
  }
}

__device__ __forceinline__ void att_store(
    char* buf, int soX, const float4* fh, const float4* fc)
{
#pragma unroll
  for (int rh = 0; rh < 2; ++rh)
#pragma unroll
    for (int sub = 0; sub < 2; ++sub) {
      const int q0 = rh * 4 + sub * 2;
      const float4 u = fh[q0], v = fc[q0];
      const float4 u2 = fh[q0 + 1], v2 = fc[q0 + 1];
      uint4 o;
      o.x = pack2(tanhf_fast(u.x + v.x), tanhf_fast(u.y + v.y));
      o.y = pack2(tanhf_fast(u.z + v.z), tanhf_fast(u.w + v.w));
      o.z = pack2(tanhf_fast(u2.x + v2.x), tanhf_fast(u2.y + v2.y));
      o.w = pack2(tanhf_fast(u2.z + v2.z), tanhf_fast(u2.w + v2.w));
      *reinterpret_cast<uint4*>(buf + sub * 8192 + rh * 4096 + soX) = o;
    }
}

__device__ __forceinline__ void gemm_att(
    const float* __restrict__ H, const float* __restrict__ C2,
    const ushort* __restrict__ W, int ldw, int n0,
    f32x4 acc[4], char* s)
{
  char* sA0 = s;
  char* sB0 = s + 16384;
  char* sA1 = s + 32768;
  char* sB1 = s + 49152;
  const int tid = threadIdx.x;
  const int lane = tid & 63;
  const int w = tid >> 6;
  const int r0 = tid >> 3;
  const int cge = (tid & 7) << 3;
  const int soX = r0 * 128 + (((tid & 7) << 4) ^ ((r0 & 7) << 4));
  const ushort* Wr0 = W + (size_t)(n0 + r0) * ldw + cge;
  const ushort* Wr1 = W + (size_t)(n0 + r0 + 32) * ldw + cge;
  const float* H0 = H + r0 * 1024 + cge;
  const float* H1 = H + (r0 + 32) * 1024 + cge;
  const float* C0 = C2 + r0 * 1024 + cge;
  const float* C1 = C2 + (r0 + 32) * 1024 + cge;

  float4 fh[8], fc[8];
  uint4 b0, b1, b2, b3;
  att_loadf(H0, H1, C0, C1, 0, fh, fc);
  att_store(sA0, soX, fh, fc);
  b0 = *reinterpret_cast<const uint4*>(Wr0);
  b1 = *reinterpret_cast<const uint4*>(Wr1);
  b2 = *reinterpret_cast<const uint4*>(Wr0 + 64);
  b3 = *reinterpret_cast<const uint4*>(Wr1 + 64);
  *reinterpret_cast<uint4*>(sB0 + soX) = b0;
  *reinterpret_cast<uint4*>(sB0 + 4096 + soX) = b1;
  *reinterpret_cast<uint4*>(sB0 + 8192 + soX) = b2;
  *reinterpret_cast<uint4*>(sB0 + 12288 + soX) = b3;
  att_loadf(H0, H1, C0, C1, 128, fh, fc);
  b0 = *reinterpret_cast<const uint4*>(Wr0 + 128);
  b1 = *reinterpret_cast<const uint4*>(Wr1 + 128);
  b2 = *reinterpret_cast<const uint4*>(Wr0 + 192);
  b3 = *reinterpret_cast<const uint4*>(Wr1 + 192);

  const int axor = (lane & 7) << 4;
  const int arow = (w * 16 + (lane & 15)) * 128;
  const int brow = (lane & 15) * 128;
  const int kb0 = (lane >> 4) << 4;
  for (int kt = 0; kt < 1024; kt += 128) {
    char* cA = (kt & 128) ? sA1 : sA0;
    char* cB = (kt & 128) ? sB1 : sB0;
    char* nA = (kt & 128) ? sA0 : sA1;
    char* nB = (kt & 128) ? sB0 : sB1;
    NMT_SYNC_LIGHT();
    if (kt + 128 < 1024) {
      att_store(nA, soX, fh, fc);
      *reinterpret_cast<uint4*>(nB + soX) = b0;
      *reinterpret_cast<uint4*>(nB + 4096 + soX) = b1;
      *reinterpret_cast<uint4*>(nB + 8192 + soX) = b2;
      *reinterpret_cast<uint4*>(nB + 12288 + soX) = b3;
      if (kt + 256 < 1024) {
        att_loadf(H0, H1, C0, C1, kt + 256, fh, fc);
        b0 = *reinterpret_cast<const uint4*>(Wr0 + kt + 256);
        b1 = *reinterpret_cast<const uint4*>(Wr1 + kt + 256);
        b2 = *reinterpret_cast<const uint4*>(Wr0 + kt + 320);
        b3 = *reinterpret_cast<const uint4*>(Wr1 + kt + 320);
      }
    }
#pragma unroll
    for (int ks = 0; ks < 4; ++ks) {
      const int sb = (ks >> 1) * 8192;
      const int kb = ((ks & 1) << 6) + kb0;
      bf16x8 af = *reinterpret_cast<const bf16x8*>(cA + sb + arow + (kb ^ axor));
#pragma unroll
      for (int nf = 0; nf < 4; ++nf) {
        bf16x8 bfr = *reinterpret_cast<const bf16x8*>(
            cB + sb + nf * 2048 + brow + (kb ^ axor));
        acc[nf] = __builtin_amdgcn_mfma_f32_16x16x32_bf16(af, bfr, acc[nf], 0, 0, 0);
      }
    }
  }
  __syncthreads();
}

__device__ __forceinline__ void store_f32(
    float* __restrict__ out, int ldo, int m0, int n0, f32x4 acc[4])
{
  const int tid = threadIdx.x, lane = tid & 63, w = tid >> 6;
  const int rbase = w * 16 + ((lane >> 4) << 2);
  const int cb = lane & 15;
#pragma unroll
  for (int nf = 0; nf < 4; ++nf)
#pragma unroll
    for (int r = 0; r < 4; ++r)
      out[(size_t)(m0 + rbase + r) * ldo + n0 + nf * 16 + cb] = acc[nf][r];
}

// LSTM cell epilogue: regroup via LDS, apply cell, store c (fp32) / h (bf16).
__device__ __forceinline__ void cell_store(
    float* smemF, f32x4 acc[4],
    float* __restrict__ c, ushort* __restrict__ hout,
    ushort* __restrict__ senc_t, int j0)
{
  const int tid = threadIdx.x, lane = tid & 63, w = tid >> 6;
  const int rbase = w * 16 + ((lane >> 4) << 2);
  const int cb = lane & 15;
  __syncthreads();
#pragma unroll
  for (int nf = 0; nf < 4; ++nf)
#pragma unroll
    for (int r = 0; r < 4; ++r)
      smemF[(rbase + r) * 68 + nf * 16 + cb] = acc[nf][r];
  __syncthreads();
#pragma unroll
  for (int i = 0; i < 4; ++i) {
    const int id = tid + i * 256;
    const int b = id >> 4, u = id & 15;
    const float g0 = smemF[b * 68 + u * 4 + 0];
    const float g1 = smemF[b * 68 + u * 4 + 1];
    const float g2 = smemF[b * 68 + u * 4 + 2];
    const float g3 = smemF[b * 68 + u * 4 + 3];
    const int off = b * 1024 + j0 + u;
    const float cold = c[off];
    const float cn = sigm(g1) * cold + sigm(g0) * tanhf_fast(g2);
    const float hv = sigm(g3) * tanhf_fast(cn);
    c[off] = cn;
    const ushort hb = f2bf(hv);
    hout[off] = hb;
    if (senc_t) senc_t[(size_t)b * 49152 + j0 + u] = hb;
  }
}

// ---------------------------------------------------------------------------
// Prologue kernels
// ---------------------------------------------------------------------------
__global__ __launch_bounds__(256) void nmt_init(
    float* c, ushort* henc, float* hbAll, float* ctxAll)
{
  const int idx = blockIdx.x * 256 + threadIdx.x;
  if (idx < 262144) c[idx] = 0.f;
  if (idx < 65536) {
    hbAll[idx] = 0.f;
    ctxAll[idx] = 0.f;
    henc[idx] = 0;
    henc[(size_t)1 * 49 * 65536 + idx] = 0;
    henc[(size_t)2 * 49 * 65536 + idx] = 0;
    henc[(size_t)3 * 49 * 65536 + idx] = 0;
  }
}

__global__ __launch_bounds__(256) void nmt_convperm(
    const float* __restrict__ in, ushort* __restrict__ out,
    int L, int Kin, int col0, int Kout)
{
  const size_t idx = (size_t)blockIdx.x * 256 + threadIdx.x;
  const size_t total = (size_t)L * 4096 * Kout;
  if (idx >= total) return;
  const int k = (int)(idx % Kout);
  const size_t rem = idx / Kout;
  const int rp = (int)(rem % 4096);
  const int l = (int)(rem / 4096);
  const int j = rp >> 2, g = rp & 3;
  out[idx] = f2bf(in[((size_t)l * 4096 + g * 1024 + j) * Kin + col0 + k]);
}

__global__ __launch_bounds__(256) void nmt_convplain(
    const float* __restrict__ in, ushort* __restrict__ out, size_t n)
{
  const size_t idx = (size_t)blockIdx.x * 256 + threadIdx.x;
  if (idx < n) out[idx] = f2bf(in[idx]);
}

__global__ __launch_bounds__(256) void nmt_bias(
    const float* __restrict__ bih, const float* __restrict__ bhh, float* __restrict__ bc)
{
  const int idx = blockIdx.x * 256 + threadIdx.x;
  if (idx >= 4 * 4096) return;
  const int rp = idx & 4095, l = idx >> 12;
  const int j = rp >> 2, g = rp & 3;
  bc[idx] = bih[l * 4096 + g * 1024 + j] + bhh[l * 4096 + g * 1024 + j];
}

__global__ __launch_bounds__(256) void nmt_gather(
    const int* __restrict__ tok, const float* __restrict__ emb,
    ushort* __restrict__ out, int rows)
{
  const size_t idx = (size_t)blockIdx.x * 256 + threadIdx.x;
  if (idx >= (size_t)rows * 512) return;
  const int k = (int)(idx & 511);
  const int r = (int)(idx >> 9);
  out[idx] = f2bf(emb[(size_t)tok[r] * 512 + k]);
}

__global__ __launch_bounds__(256) void nmt_pre(
    const ushort* __restrict__ A, const ushort* __restrict__ Wp,
    const float* __restrict__ bc0, float* __restrict__ out, int K)
{
  __shared__ __align__(16) char smem[SMEM_BYTES];
  const int m0 = blockIdx.x * 64, n0 = blockIdx.y * 64;
  const int lane = threadIdx.x & 63;
  const int cb = lane & 15;
  f32x4 acc[4];
#pragma unroll
  for (int nf = 0; nf < 4; ++nf) {
    const float bv = bc0[n0 + nf * 16 + cb];
#pragma unroll
    for (int r = 0; r < 4; ++r) acc[nf][r] = bv;
  }
  gemm_term(A, K, Wp, K, K, m0, n0, acc, smem);
  store_f32(out, 4096, m0, n0, acc);
}

__global__ __launch_bounds__(256) void nmt_decinit(
    const ushort* __restrict__ henc, float* c, ushort* h)
{
  const int idx = blockIdx.x * 256 + threadIdx.x;
  if (idx >= 65536) return;
  const ushort hv = henc[((size_t)3 * 49 + 48) * 65536 + idx];
  const float cv = c[3 * 65536 + idx];
  c[idx] = cv; c[65536 + idx] = cv; c[2 * 65536 + idx] = cv;
  h[idx] = hv; h[65536 + idx] = hv; h[2 * 65536 + idx] = hv; h[3 * 65536 + idx] = hv;
}

// SV precompute: SV[b][s][:] = senc[b][s][:] @ attW2^T  (rows s<48 stored)
__global__ __launch_bounds__(256) void nmt_sv(
    const ushort* __restrict__ senc, const ushort* __restrict__ attW,
    ushort* __restrict__ SV)
{
  __shared__ __align__(16) char smem[SMEM_BYTES];
  const int b = blockIdx.x;
  const int n0 = blockIdx.y * 64;
  const int tid = threadIdx.x, lane = tid & 63, w = tid >> 6;
  const int rbase = w * 16 + ((lane >> 4) << 2), cb = lane & 15;
  f32x4 acc[4];
#pragma unroll
  for (int nf = 0; nf < 4; ++nf)
#pragma unroll
    for (int r = 0; r < 4; ++r) acc[nf][r] = 0.f;
  gemm_term(senc + (size_t)b * 49152, 1024, attW + 1024, 2048, 1024, 0, n0,
            acc, smem);
#pragma unroll
  for (int nf = 0; nf < 4; ++nf)
#pragma unroll
    for (int r = 0; r < 4; ++r) {
      const int row = rbase + r;
      if (row < 48)
        SV[(size_t)b * 49152 + row * 1024 + n0 + nf * 16 + cb] = f2bf(acc[nf][r]);
    }
}

// ---------------------------------------------------------------------------
// Encoder wavefront cell
// ---------------------------------------------------------------------------
__global__ __launch_bounds__(256) void nmt_enc_cell(
    int u, int lo, ushort* __restrict__ henc, ushort* __restrict__ srcenc,
    float* __restrict__ c,
    const ushort* __restrict__ WihR, const ushort* __restrict__ Whh,
    const float* __restrict__ X0, const float* __restrict__ bcE)
{
  __shared__ __align__(16) char smem[SMEM_BYTES];
  const int l = lo + blockIdx.y;
  const int t = u - l;
  const int n0 = blockIdx.x * 64;
  const int tid = threadIdx.x, lane = tid & 63, w = tid >> 6;
  const int rbase = w * 16 + ((lane >> 4) << 2), cb = lane & 15;
  f32x4 acc[4];
  if (l == 0) {
#pragma unroll
    for (int nf = 0; nf < 4; ++nf)
#pragma unroll
      for (int r = 0; r < 4; ++r)
        acc[nf][r] = X0[(size_t)t * 262144 + (size_t)(rbase + r) * 4096 + n0 + nf * 16 + cb];
  } else {
#pragma unroll
    for (int nf = 0; nf < 4; ++nf) {
      const float bv = bcE[l * 4096 + n0 + nf * 16 + cb];
#pragma unroll
      for (int r = 0; r < 4; ++r) acc[nf][r] = bv;
    }
    gemm_term(henc + ((size_t)(l - 1) * 49 + t + 1) * 65536, 1024,
              WihR + (size_t)(l - 1) * 4194304, 1024, 1024, 0, n0, acc, smem);
  }
  gemm_term(henc + ((size_t)l * 49 + t) * 65536, 1024,
            Whh + (size_t)l * 4194304, 1024, 1024, 0, n0, acc, smem);
  cell_store((float*)smem, acc, c + l * 65536,
             henc + ((size_t)l * 49 + t + 1) * 65536,
             (l == 3) ? (srcenc + t * 1024) : (ushort*)nullptr, n0 >> 2);
}

// ---------------------------------------------------------------------------
// Decoder stage l (grid 64 x 2), R7 role layout; S0 cell uses gemm_att.
// ---------------------------------------------------------------------------
__global__ __launch_bounds__(256) void nmt_dec_stage(
    int l, const ushort* __restrict__ hp, ushort* __restrict__ hn,
    float* __restrict__ c,
    const ushort* __restrict__ Whh, const ushort* __restrict__ WihR,
    const ushort* __restrict__ Wd0a,
    const float* __restrict__ hbprev, const float* __restrict__ ctxprev,
    const float* __restrict__ Y0t, const float* __restrict__ bcD,
    float* __restrict__ pbuf)
{
  __shared__ __align__(16) char smem[SMEM_A];
  const int n0 = blockIdx.x * 64;
  const int tid = threadIdx.x, lane = tid & 63, w = tid >> 6;
  const int rbase = w * 16 + ((lane >> 4) << 2), cb = lane & 15;
  f32x4 acc[4];
  if (blockIdx.y == 0) {
    if (l == 0) {
#pragma unroll
      for (int nf = 0; nf < 4; ++nf)
#pragma unroll
        for (int r = 0; r < 4; ++r) {
          const size_t o = (size_t)(rbase + r) * 4096 + n0 + nf * 16 + cb;
          acc[nf][r] = Y0t[o] + pbuf[o];
        }
      gemm_att(hbprev, ctxprev, Wd0a, 1024, n0, acc, smem);
    } else {
#pragma unroll
      for (int nf = 0; nf < 4; ++nf)
#pragma unroll
        for (int r = 0; r < 4; ++r)
          acc[nf][r] = pbuf[(size_t)l * 262144 + (size_t)(rbase + r) * 4096 + n0 + nf * 16 + cb];
      gemm_term(hn + (l - 1) * 65536, 1024, WihR + (size_t)(l - 1) * 4194304,
                1024, 1024, 0, n0, acc, smem);
    }
    cell_store((float*)smem, acc, c + l * 65536, hn + l * 65536,
               (ushort*)nullptr, n0 >> 2);
  } else {
    const int lp = (l + 1) & 3;
    if (lp == 0) {
#pragma unroll
      for (int nf = 0; nf < 4; ++nf)
#pragma unroll
        for (int r = 0; r < 4; ++r) acc[nf][r] = 0.f;
      gemm_term(hn, 1024, Whh, 1024, 1024, 0, n0, acc, smem);
    } else {
#pragma unroll
      for (int nf = 0; nf < 4; ++nf) {
        const float bv = bcD[lp * 4096 + n0 + nf * 16 + cb];
#pragma unroll
        for (int r = 0; r < 4; ++r) acc[nf][r] = bv;
      }
      gemm_term(hp + lp * 65536, 1024, Whh + (size_t)lp * 4194304,
                1024, 1024, 0, n0, acc, smem);
    }
    store_f32(pbuf + (size_t)lp * 262144, 4096, 0, n0, acc);
  }
}

// one-off: pbuf0 = Whh0 * h0(init) before step 0
__global__ __launch_bounds__(256) void nmt_partial0(
    const ushort* __restrict__ h0, const ushort* __restrict__ Whh0,
    float* __restrict__ pbuf)
{
  __shared__ __align__(16) char smem[SMEM_BYTES];
  const int n0 = blockIdx.x * 64;
  f32x4 acc[4];
#pragma unroll
  for (int nf = 0; nf < 4; ++nf)
#pragma unroll
    for (int r = 0; r < 4; ++r) acc[nf][r] = 0.f;
  gemm_term(h0, 1024, Whh0, 1024, 1024, 0, n0, acc, smem);
  store_f32(pbuf, 4096, 0, n0, acc);
}

// Stage A: blocks 0..63 attnA (scores/softmax/ctx2); blocks 64..79 HB gemm.
// Writes f32 slots (t+1) of ctxAll / hbAll.
__global__ __launch_bounds__(256) void nmt_attnAB(
    const ushort* __restrict__ h3, const ushort* __restrict__ senc,
    const ushort* __restrict__ SV, const ushort* __restrict__ attW,
    float* __restrict__ ctx2, float* __restrict__ hb)
{
  __shared__ __align__(16) char smem[SMEM_BYTES];
  const int bid = blockIdx.x;
  const int tid = threadIdx.x, lane = tid & 63, w = tid >> 6;
  if (bid < 64) {
    float* sc = (float*)smem;
    float* al = (float*)smem + 64;
    const int b = bid;
    const ushort* sb = senc + (size_t)b * 49152;
    const ushort* vb = SV + (size_t)b * 49152;
    float hreg[16];
#pragma unroll
    for (int q = 0; q < 16; ++q) hreg[q] = bf2f(h3[b * 1024 + lane * 16 + q]);
    for (int s = w; s < 48; s += 4) {
      const ushort* vr = sb + s * 1024 + lane * 16;
      float p = 0.f;
#pragma unroll
      for (int q = 0; q < 16; ++q) p += bf2f(vr[q]) * hreg[q];
      for (int d = 1; d < 64; d <<= 1) p += __shfl_xor(p, d);
      if (lane == 0) sc[s] = p;
    }
    __syncthreads();
    if (tid < 64) {
      const float v = (lane < 48) ? sc[lane] : -3.4e38f;
      float m = v;
      for (int d = 1; d < 64; d <<= 1) m = fmaxf(m, __shfl_xor(m, d));
      float e = (lane < 48) ? expf(v - m) : 0.f;
      float s = e;
      for (int d = 1; d < 64; d <<= 1) s += __shfl_xor(s, d);
      al[lane] = e / s;
    }
    __syncthreads();
    const int k0 = tid * 4;
    float a0 = 0, a1 = 0, a2 = 0, a3 = 0;
    for (int s = 0; s < 48; ++s) {
      const float als = al[s];
      const ushort* vr = vb + s * 1024 + k0;
      a0 += als * bf2f(vr[0]); a1 += als * bf2f(vr[1]);
      a2 += als * bf2f(vr[2]); a3 += als * bf2f(vr[3]);
    }
    ctx2[b * 1024 + k0 + 0] = a0; ctx2[b * 1024 + k0 + 1] = a1;
    ctx2[b * 1024 + k0 + 2] = a2; ctx2[b * 1024 + k0 + 3] = a3;
  } else {
    const int n0 = (bid - 64) * 64;
    f32x4 acc[4];
#pragma unroll
    for (int nf = 0; nf < 4; ++nf)
#pragma unroll
      for (int r = 0; r < 4; ++r) acc[nf][r] = 0.f;
    gemm_term(h3, 1024, attW, 2048, 1024, 0, n0, acc, smem);
    store_f32(hb, 1024, 0, n0, acc);
  }
}

// batch attves: attves[t][i] = tanh(hbAll[t+1][i] + ctxAll[t+1][i])
__global__ __launch_bounds__(256) void nmt_attves_k(
    const float* __restrict__ hbAll, const float* __restrict__ ctxAll,
    ushort* __restrict__ attves)
{
  const int i = blockIdx.x * 1024 + threadIdx.x * 4;
#pragma unroll
  for (int k = 0; k < 4; ++k) {
    const int j = i + k;
    attves[j] = f2bf(tanhf_fast(hbAll[j + 65536] + ctxAll[j + 65536]));
  }
}

// ---------------------------------------------------------------------------
// Readout v4 (R15): M-tile 2, depth-2 pipelined light-sync rounds.
// Grid (24 m-groups, 500 n-tiles). LDS 48KB: 2 slots x {A0,A1,B} x 8KB.
// ---------------------------------------------------------------------------
__global__ __launch_bounds__(256) void nmt_readout(
    const ushort* __restrict__ attves, const ushort* __restrict__ routW,
    const int* __restrict__ tgt, float* __restrict__ pmax,
    float* __restrict__ psum, float* __restrict__ goldl)
{
  __shared__ __align__(16) char smem[SMEM_RO];
  const int g = blockIdx.x;
  const int n0 = blockIdx.y * 64;
  const int tid = threadIdx.x, lane = tid & 63, w = tid >> 6;
  const int rbase = w * 16 + ((lane >> 4) << 2), cb = lane & 15;
  const int r0 = tid >> 3;
  const int cge = (tid & 7) << 3;
  const int soX = r0 * 128 + (((tid & 7) << 4) ^ ((r0 & 7) << 4));
  const int axor = (lane & 7) << 4;
  const int arow = (w * 16 + (lane & 15)) * 128;
  const int brow = (lane & 15) * 128;
  const int kb0 = (lane >> 4) << 4;

  const ushort* A0r0 = attves + (size_t)(g * 128 + r0) * 1024 + cge;
  const ushort* A0r1 = attves + (size_t)(g * 128 + r0 + 32) * 1024 + cge;
  const ushort* A1r0 = attves + (size_t)(g * 128 + 64 + r0) * 1024 + cge;
  const ushort* A1r1 = attves + (size_t)(g * 128 + 64 + r0 + 32) * 1024 + cge;
  const ushort* Br0  = routW + (size_t)(n0 + r0) * 1024 + cge;
  const ushort* Br1  = routW + (size_t)(n0 + r0 + 32) * 1024 + cge;

  f32x4 acc[2][4];
#pragma unroll
  for (int mi = 0; mi < 2; ++mi)
#pragma unroll
    for (int nf = 0; nf < 4; ++nf)
#pragma unroll
      for (int r = 0; r < 4; ++r) acc[mi][nf][r] = 0.f;

  uint4 ra0 = *(const uint4*)(A0r0);
  uint4 ra1 = *(const uint4*)(A0r1);
  uint4 ra2 = *(const uint4*)(A1r0);
  uint4 ra3 = *(const uint4*)(A1r1);
  uint4 rb0 = *(const uint4*)(Br0);
  uint4 rb1 = *(const uint4*)(Br1);
  {
    char* sl = smem;
    *(uint4*)(sl + soX) = ra0;          *(uint4*)(sl + 4096 + soX) = ra1;
    *(uint4*)(sl + 8192 + soX) = ra2;   *(uint4*)(sl + 12288 + soX) = ra3;
    *(uint4*)(sl + 16384 + soX) = rb0;  *(uint4*)(sl + 20480 + soX) = rb1;
  }
  ra0 = *(const uint4*)(A0r0 + 64);
  ra1 = *(const uint4*)(A0r1 + 64);
  ra2 = *(const uint4*)(A1r0 + 64);
  ra3 = *(const uint4*)(A1r1 + 64);
  rb0 = *(const uint4*)(Br0 + 64);
  rb1 = *(const uint4*)(Br1 + 64);

  for (int kt = 0; kt < 1024; kt += 64) {
    NMT_SYNC_LIGHT();
    if (kt + 64 < 1024) {
      char* sl = smem + ((((kt >> 6) + 1) & 1) ? 24576 : 0);
      *(uint4*)(sl + soX) = ra0;          *(uint4*)(sl + 4096 + soX) = ra1;
      *(uint4*)(sl + 8192 + soX) = ra2;   *(uint4*)(sl + 12288 + soX) = ra3;
      *(uint4*)(sl + 16384 + soX) = rb0;  *(uint4*)(sl + 20480 + soX) = rb1;
      if (kt + 128 < 1024) {
        ra0 = *(const uint4*)(A0r0 + kt + 128);
        ra1 = *(const uint4*)(A0r1 + kt + 128);
        ra2 = *(const uint4*)(A1r0 + kt + 128);
        ra3 = *(const uint4*)(A1r1 + kt + 128);
        rb0 = *(const uint4*)(Br0 + kt + 128);
        rb1 = *(const uint4*)(Br1 + kt + 128);
      }
    }
    char* cur = smem + (((kt >> 6) & 1) ? 24576 : 0);
#pragma unroll
    for (int ks = 0; ks < 2; ++ks) {
      const int kb = (ks << 6) + kb0;
      bf16x8 bf0 = *(const bf16x8*)(cur + 16384 + 0 * 2048 + brow + (kb ^ axor));
      bf16x8 bf1 = *(const bf16x8*)(cur + 16384 + 1 * 2048 + brow + (kb ^ axor));
      bf16x8 bf2 = *(const bf16x8*)(cur + 16384 + 2 * 2048 + brow + (kb ^ axor));
      bf16x8 bf3 = *(const bf16x8*)(cur + 16384 + 3 * 2048 + brow + (kb ^ axor));
      bf16x8 af0 = *(const bf16x8*)(cur + arow + (kb ^ axor));
      bf16x8 af1 = *(const bf16x8*)(cur + 8192 + arow + (kb ^ axor));
      acc[0][0] = __builtin_amdgcn_mfma_f32_16x16x32_bf16(af0, bf0, acc[0][0], 0, 0, 0);
      acc[0][1] = __builtin_amdgcn_mfma_f32_16x16x32_bf16(af0, bf1, acc[0][1], 0, 0, 0);
      acc[0][2] = __builtin_amdgcn_mfma_f32_16x16x32_bf16(af0, bf2, acc[0][2], 0, 0, 0);
      acc[0][3] = __builtin_amdgcn_mfma_f32_16x16x32_bf16(af0, bf3, acc[0][3], 0, 0, 0);
      acc[1][0] = __builtin_amdgcn_mfma_f32_16x16x32_bf16(af1, bf0, acc[1][0], 0, 0, 0);
      acc[1][1] = __builtin_amdgcn_mfma_f32_16x16x32_bf16(af1, bf1, acc[1][1], 0, 0, 0);
      acc[1][2] = __builtin_amdgcn_mfma_f32_16x16x32_bf16(af1, bf2, acc[1][2], 0, 0, 0);
      acc[1][3] = __builtin_amdgcn_mfma_f32_16x16x32_bf16(af1, bf3, acc[1][3], 0, 0, 0);
    }
  }

#pragma unroll
  for (int mi = 0; mi < 2; ++mi) {
    const int gm = g * 2 + mi;
    if (gm >= 47) continue;
#pragma unroll
    for (int r = 0; r < 4; ++r) {
      float lm = fmaxf(fmaxf(acc[mi][0][r], acc[mi][1][r]),
                       fmaxf(acc[mi][2][r], acc[mi][3][r]));
      for (int d = 1; d < 16; d <<= 1) lm = fmaxf(lm, __shfl_xor(lm, d));
      float ls = 0.f;
#pragma unroll
      for (int nf = 0; nf < 4; ++nf) ls += expf(acc[mi][nf][r] - lm);
      for (int d = 1; d < 16; d <<= 1) ls += __shfl_xor(ls, d);
      const int grow = gm * 64 + rbase + r;
      if (cb == 0) {
        pmax[(size_t)grow * 500 + blockIdx.y] = lm;
        psum[(size_t)grow * 500 + blockIdx.y] = ls;
      }
      const int t = grow >> 6, b = grow & 63;
      const int gold = tgt[(t + 1) * 64 + b];
#pragma unroll
      for (int nf = 0; nf < 4; ++nf)
        if (n0 + nf * 16 + cb == gold) goldl[grow] = acc[mi][nf][r];
    }
  }
}

__global__ __launch_bounds__(64) void nmt_combine(
    const float* __restrict__ pmax, const float* __restrict__ psum,
    const float* __restrict__ goldl, const int* __restrict__ tgt,
    float* __restrict__ lpm)
{
  const int row = blockIdx.x;
  const int lane = threadIdx.x;
  float m = -3.4e38f, s = 0.f;
  for (int i = lane; i < 500; i += 64) {
    const float pm = pmax[(size_t)row * 500 + i];
    const float ps = psum[(size_t)row * 500 + i];
    if (pm > m) { s = s * expf(m - pm) + ps; m = pm; }
    else        { s += ps * expf(pm - m); }
  }
  for (int d = 1; d < 64; d <<= 1) {
    const float om = __shfl_xor(m, d), os = __shfl_xor(s, d);
    if (om > m) { s = s * expf(m - om) + os; m = om; }
    else        { s += os * expf(om - m); }
  }
  if (lane == 0) {
    const int t = row >> 6, b = row & 63;
    const int gold = tgt[(t + 1) * 64 + b];
    const float lp = goldl[row] - m - logf(s);
    lpm[row] = (gold != 0) ? lp : 0.f;
  }
}

__global__ __launch_bounds__(64) void nmt_final(
    const float* __restrict__ lpm, float* __restrict__ out)
{
  const int b = threadIdx.x;
  float s = 0.f;
  for (int t = 0; t < 47; ++t) s += lpm[t * 64 + b];
  out[b] = s;
}

// ===========================================================================
extern "C" void kernel_launch(void* const* d_in, const int* in_sizes, int n_in,
                              void* d_out, int out_size, void* d_ws, size_t ws_size,
                              hipStream_t stream)
{
  (void)in_sizes; (void)n_in; (void)out_size; (void)ws_size;
  const int*   src_tok  = (const int*)d_in[0];
  const int*   tgt_tok  = (const int*)d_in[1];
  const float* src_emb  = (const float*)d_in[2];
  const float* tgt_emb  = (const float*)d_in[3];
  const float* eWih0    = (const float*)d_in[4];
  const float* eWihR    = (const float*)d_in[5];
  const float* eWhh     = (const float*)d_in[6];
  const float* ebih     = (const float*)d_in[7];
  const float* ebhh     = (const float*)d_in[8];
  const float* dWih0    = (const float*)d_in[9];
  const float* dWihR    = (const float*)d_in[10];
  const float* dWhh     = (const float*)d_in[11];
  const float* dbih     = (const float*)d_in[12];
  const float* dbhh     = (const float*)d_in[13];
  const float* attW_f   = (const float*)d_in[14];
  const float* routW_f  = (const float*)d_in[15];

  // ---- workspace carve (deterministic) ----
  char* p = (char*)d_ws;
  auto alloc = [&](size_t bytes) { void* r = (void*)p; p += (bytes + 255) & ~(size_t)255; return r; };
  ushort* eWih0p = (ushort*)alloc((size_t)4096 * 512 * 2);
  ushort* eWihRp = (ushort*)alloc((size_t)3 * 4096 * 1024 * 2);
  ushort* eWhhp  = (ushort*)alloc((size_t)4 * 4096 * 1024 * 2);
  ushort* dWih0y = (ushort*)alloc((size_t)4096 * 512 * 2);
  ushort* dWih0a = (ushort*)alloc((size_t)4096 * 1024 * 2);
  ushort* dWihRp = (ushort*)alloc((size_t)3 * 4096 * 1024 * 2);
  ushort* dWhhp  = (ushort*)alloc((size_t)4 * 4096 * 1024 * 2);
  ushort* attWb  = (ushort*)alloc((size_t)1024 * 2048 * 2);
  ushort* routWb = (ushort*)alloc((size_t)32000 * 1024 * 2);
  ushort* srcx   = (ushort*)alloc((size_t)3072 * 512 * 2);
  ushort* tgtx   = (ushort*)alloc((size_t)3008 * 512 * 2);
  ushort* henc   = (ushort*)alloc((size_t)4 * 49 * 65536 * 2);
  ushort* hA     = (ushort*)alloc((size_t)4 * 65536 * 2);
  ushort* hB     = (ushort*)alloc((size_t)4 * 65536 * 2);
  ushort* srcenc = (ushort*)alloc((size_t)64 * 49152 * 2);
  ushort* SVbuf  = (ushort*)alloc((size_t)64 * 49152 * 2);
  ushort* attves = (ushort*)alloc((size_t)3072 * 1024 * 2);   // padded rows
  float*  hbAll  = (float*)alloc((size_t)48 * 65536 * 4);
  float*  ctxAll = (float*)alloc((size_t)48 * 65536 * 4);
  float*  pbuf   = (float*)alloc((size_t)4 * 262144 * 4);
  float*  X0     = (float*)alloc((size_t)3072 * 4096 * 4);
  float*  Y0     = (float*)alloc((size_t)3008 * 4096 * 4);
  float*  bcE    = (float*)alloc((size_t)16384 * 4);
  float*  bcD    = (float*)alloc((size_t)16384 * 4);
  float*  cbuf   = (float*)alloc((size_t)4 * 65536 * 4);
  float*  pmaxb  = (float*)alloc((size_t)3008 * 500 * 4);
  float*  psumb  = (float*)alloc((size_t)3008 * 500 * 4);
  float*  goldl  = (float*)alloc((size_t)3008 * 4);
  float*  lpm    = (float*)alloc((size_t)3008 * 4);

  const dim3 B256(256);
  auto g1 = [](size_t n) { return dim3((unsigned)((n + 255) / 256)); };

  nmt_init<<<g1(262144), B256, 0, stream>>>(cbuf, henc, hbAll, ctxAll);

  nmt_convperm<<<g1((size_t)4096 * 512), B256, 0, stream>>>(eWih0, eWih0p, 1, 512, 0, 512);
  nmt_convperm<<<g1((size_t)3 * 4096 * 1024), B256, 0, stream>>>(eWihR, eWihRp, 3, 1024, 0, 1024);
  nmt_convperm<<<g1((size_t)4 * 4096 * 1024), B256, 0, stream>>>(eWhh, eWhhp, 4, 1024, 0, 1024);
  nmt_convperm<<<g1((size_t)4096 * 512), B256, 0, stream>>>(dWih0, dWih0y, 1, 1536, 0, 512);
  nmt_convperm<<<g1((size_t)4096 * 1024), B256, 0, stream>>>(dWih0, dWih0a, 1, 1536, 512, 1024);
  nmt_convperm<<<g1((size_t)3 * 4096 * 1024), B256, 0, stream>>>(dWihR, dWihRp, 3, 1024, 0, 1024);
  nmt_convperm<<<g1((size_t)4 * 4096 * 1024), B256, 0, stream>>>(dWhh, dWhhp, 4, 1024, 0, 1024);
  nmt_convplain<<<g1((size_t)1024 * 2048), B256, 0, stream>>>(attW_f, attWb, (size_t)1024 * 2048);
  nmt_convplain<<<g1((size_t)32000 * 1024), B256, 0, stream>>>(routW_f, routWb, (size_t)32000 * 1024);
  nmt_bias<<<g1(16384), B256, 0, stream>>>(ebih, ebhh, bcE);
  nmt_bias<<<g1(16384), B256, 0, stream>>>(dbih, dbhh, bcD);
  nmt_gather<<<g1((size_t)3072 * 512), B256, 0, stream>>>(src_tok, src_emb, srcx, 3072);
  nmt_gather<<<g1((size_t)3008 * 512), B256, 0, stream>>>(tgt_tok, tgt_emb, tgtx, 3008);

  nmt_pre<<<dim3(48, 64), B256, 0, stream>>>(srcx, eWih0p, bcE, X0, 512);
  nmt_pre<<<dim3(47, 64), B256, 0, stream>>>(tgtx, dWih0y, bcD, Y0, 512);

  // ---- encoder wavefront ----
  for (int u = 0; u < 51; ++u) {
    const int lo = (u > 47) ? (u - 47) : 0;
    const int hi = (u < 3) ? u : 3;
    nmt_enc_cell<<<dim3(64, hi - lo + 1), B256, 0, stream>>>(
        u, lo, henc, srcenc, cbuf, eWihRp, eWhhp, X0, bcE);
  }
  nmt_decinit<<<g1(65536), B256, 0, stream>>>(henc, cbuf, hA);
  nmt_sv<<<dim3(64, 16), B256, 0, stream>>>(srcenc, attWb, SVbuf);
  nmt_partial0<<<dim3(64), B256, 0, stream>>>(hA, dWhhp, pbuf);

  // ---- decoder scan: 5 hops per step (4 stages + attnAB) ----
  for (int t = 0; t < 47; ++t) {
    ushort* hp = (t & 1) ? hB : hA;
    ushort* hn = (t & 1) ? hA : hB;
    for (int l = 0; l < 4; ++l) {
      nmt_dec_stage<<<dim3(64, 2), B256, 0, stream>>>(
          l, hp, hn, cbuf, dWhhp, dWihRp, dWih0a,
          hbAll + (size_t)t * 65536, ctxAll + (size_t)t * 65536,
          Y0 + (size_t)t * 262144, bcD, pbuf);
    }
    nmt_attnAB<<<dim3(80), B256, 0, stream>>>(
        hn + 3 * 65536, srcenc, SVbuf, attWb,
        ctxAll + (size_t)(t + 1) * 65536, hbAll + (size_t)(t + 1) * 65536);
  }
  nmt_attves_k<<<dim3(3008), B256, 0, stream>>>(hbAll, ctxAll, attves);

  // ---- readout (pipelined, M-tile 2) + log-softmax + masked gold sum ----
  nmt_readout<<<dim3(24, 500), B256, 0, stream>>>(attves, routWb, tgt_tok,
                                                  pmaxb, psumb, goldl);
  nmt_combine<<<dim3(3008), dim3(64), 0, stream>>>(pmaxb, psumb, goldl, tgt_tok, lpm);
  nmt_final<<<dim3(1), dim3(64), 0, stream>>>(lpm, (float*)d_out);
}

// Round 17
// 3993.086 us; speedup vs baseline: 1.1702x; 1.1702x over previous
//
#include <hip/hip_runtime.h>

// ============================================================================
// NMT seq2seq forward — Round 17: R15 base (best: 4191 us) + skewed (slope-2)
// encoder wavefront with look-ahead Wih partials (R13's encoder arm, now
// isolated from the bad 8x readout it was bundled with).
// E=512 H=1024 L=4 V=32000 B=64 SS=48 TT=48 (dec steps = 47)
// ============================================================================

typedef __attribute__((ext_vector_type(8))) short bf16x8;
typedef __attribute__((ext_vector_type(4))) float f32x4;

#define SMEM_BYTES 32768  // gemm core: 4 swizzled 8KB tiles
#define SMEM_RO    49152  // readout: 2 slots x (2 A-tiles + B-tile) x 8KB

#define NMT_SYNC_LIGHT()                                   \
  do {                                                     \
    asm volatile("s_waitcnt lgkmcnt(0)" ::: "memory");     \
    __builtin_amdgcn_s_barrier();                          \
    __builtin_amdgcn_sched_barrier(0);                     \
  } while (0)

__device__ __forceinline__ float bf2f(ushort u) {
  union { uint i; float f; } v; v.i = ((uint)u) << 16; return v.f;
}
__device__ __forceinline__ ushort f2bf(float x) {
  union { float f; uint i; } v; v.f = x;
  uint r = (v.i + 0x7fffu + ((v.i >> 16) & 1u)) >> 16;
  return (ushort)r;
}
__device__ __forceinline__ float sigm(float x) {
  return __fdividef(1.f, 1.f + __expf(-x));
}
__device__ __forceinline__ float tanhf_fast(float x) {
  const float e = __expf(2.f * x);
  return 1.f - __fdividef(2.f, e + 1.f);
}

// ---------------------------------------------------------------------------
// Pipelined swizzled GEMM core (R7): acc += A[m0..+64,:K] @ W[n0..+64,:K]^T
// ---------------------------------------------------------------------------
__device__ __forceinline__ void gemm_term(
    const ushort* __restrict__ A, int lda,
    const ushort* __restrict__ W, int ldw,
    int K, int m0, int n0,
    f32x4 acc[4], char* s)
{
  char* sA0 = s;
  char* sB0 = s + 8192;
  char* sA1 = s + 16384;
  char* sB1 = s + 24576;
  const int tid = threadIdx.x;
  const int lane = tid & 63;
  const int w = tid >> 6;
  const int r0 = tid >> 3;
  const int cge = (tid & 7) << 3;
  const ushort* Arow0 = A + (size_t)(m0 + r0) * lda + cge;
  const ushort* Arow1 = A + (size_t)(m0 + r0 + 32) * lda + cge;
  const ushort* Wrow0 = W + (size_t)(n0 + r0) * ldw + cge;
  const ushort* Wrow1 = W + (size_t)(n0 + r0 + 32) * ldw + cge;
  const int so0 = r0 * 128 + (((tid & 7) << 4) ^ ((r0 & 7) << 4));
  const int so1 = so0 + 4096;

  uint4 a0 = *reinterpret_cast<const uint4*>(Arow0);
  uint4 a1 = *reinterpret_cast<const uint4*>(Arow1);
  uint4 b0 = *reinterpret_cast<const uint4*>(Wrow0);
  uint4 b1 = *reinterpret_cast<const uint4*>(Wrow1);
  *reinterpret_cast<uint4*>(sA0 + so0) = a0;
  *reinterpret_cast<uint4*>(sA0 + so1) = a1;
  *reinterpret_cast<uint4*>(sB0 + so0) = b0;
  *reinterpret_cast<uint4*>(sB0 + so1) = b1;
  if (K > 64) {
    a0 = *reinterpret_cast<const uint4*>(Arow0 + 64);
    a1 = *reinterpret_cast<const uint4*>(Arow1 + 64);
    b0 = *reinterpret_cast<const uint4*>(Wrow0 + 64);
    b1 = *reinterpret_cast<const uint4*>(Wrow1 + 64);
  }
  const int axor = (lane & 7) << 4;
  const int arow = (w * 16 + (lane & 15)) * 128;
  const int brow = (lane & 15) * 128;
  const int kb0 = (lane >> 4) << 4;
  for (int kt = 0; kt < K; kt += 64) {
    char* cA = (kt & 64) ? sA1 : sA0;
    char* cB = (kt & 64) ? sB1 : sB0;
    char* nA = (kt & 64) ? sA0 : sA1;
    char* nB = (kt & 64) ? sB0 : sB1;
    __syncthreads();
    if (kt + 64 < K) {
      *reinterpret_cast<uint4*>(nA + so0) = a0;
      *reinterpret_cast<uint4*>(nA + so1) = a1;
      *reinterpret_cast<uint4*>(nB + so0) = b0;
      *reinterpret_cast<uint4*>(nB + so1) = b1;
      if (kt + 128 < K) {
        a0 = *reinterpret_cast<const uint4*>(Arow0 + kt + 128);
        a1 = *reinterpret_cast<const uint4*>(Arow1 + kt + 128);
        b0 = *reinterpret_cast<const uint4*>(Wrow0 + kt + 128);
        b1 = *reinterpret_cast<const uint4*>(Wrow1 + kt + 128);
      }
    }
#pragma unroll
    for (int ks = 0; ks < 2; ++ks) {
      const int kb = ks * 64 + kb0;
      bf16x8 af = *reinterpret_cast<const bf16x8*>(cA + arow + (kb ^ axor));
#pragma unroll
      for (int nf = 0; nf < 4; ++nf) {
        bf16x8 bfr = *reinterpret_cast<const bf16x8*>(
            cB + nf * 2048 + brow + (kb ^ axor));
        acc[nf] = __builtin_amdgcn_mfma_f32_16x16x32_bf16(af, bfr, acc[nf], 0, 0, 0);
      }
    }
  }
  __syncthreads();
}

__device__ __forceinline__ void store_f32(
    float* __restrict__ out, int ldo, int m0, int n0, f32x4 acc[4])
{
  const int tid = threadIdx.x, lane = tid & 63, w = tid >> 6;
  const int rbase = w * 16 + ((lane >> 4) << 2);
  const int cb = lane & 15;
#pragma unroll
  for (int nf = 0; nf < 4; ++nf)
#pragma unroll
    for (int r = 0; r < 4; ++r)
      out[(size_t)(m0 + rbase + r) * ldo + n0 + nf * 16 + cb] = acc[nf][r];
}

// LSTM cell epilogue: regroup via LDS, apply cell, store c (fp32) / h (bf16).
__device__ __forceinline__ void cell_store(
    float* smemF, f32x4 acc[4],
    float* __restrict__ c, ushort* __restrict__ hout,
    ushort* __restrict__ senc_t, int j0)
{
  const int tid = threadIdx.x, lane = tid & 63, w = tid >> 6;
  const int rbase = w * 16 + ((lane >> 4) << 2);
  const int cb = lane & 15;
  __syncthreads();
#pragma unroll
  for (int nf = 0; nf < 4; ++nf)
#pragma unroll
    for (int r = 0; r < 4; ++r)
      smemF[(rbase + r) * 68 + nf * 16 + cb] = acc[nf][r];
  __syncthreads();
#pragma unroll
  for (int i = 0; i < 4; ++i) {
    const int id = tid + i * 256;
    const int b = id >> 4, u = id & 15;
    const float g0 = smemF[b * 68 + u * 4 + 0];
    const float g1 = smemF[b * 68 + u * 4 + 1];
    const float g2 = smemF[b * 68 + u * 4 + 2];
    const float g3 = smemF[b * 68 + u * 4 + 3];
    const int off = b * 1024 + j0 + u;
    const float cold = c[off];
    const float cn = sigm(g1) * cold + sigm(g0) * tanhf_fast(g2);
    const float hv = sigm(g3) * tanhf_fast(cn);
    c[off] = cn;
    const ushort hb = f2bf(hv);
    hout[off] = hb;
    if (senc_t) senc_t[(size_t)b * 49152 + j0 + u] = hb;
  }
}

// ---------------------------------------------------------------------------
// Prologue kernels
// ---------------------------------------------------------------------------
__global__ __launch_bounds__(256) void nmt_init(float* c, ushort* henc, ushort* attbf)
{
  const int idx = blockIdx.x * 256 + threadIdx.x;
  if (idx < 262144) c[idx] = 0.f;
  if (idx < 65536) {
    attbf[idx] = 0;
    henc[idx] = 0;
    henc[(size_t)1 * 49 * 65536 + idx] = 0;
    henc[(size_t)2 * 49 * 65536 + idx] = 0;
    henc[(size_t)3 * 49 * 65536 + idx] = 0;
  }
}

__global__ __launch_bounds__(256) void nmt_convperm(
    const float* __restrict__ in, ushort* __restrict__ out,
    int L, int Kin, int col0, int Kout)
{
  const size_t idx = (size_t)blockIdx.x * 256 + threadIdx.x;
  const size_t total = (size_t)L * 4096 * Kout;
  if (idx >= total) return;
  const int k = (int)(idx % Kout);
  const size_t rem = idx / Kout;
  const int rp = (int)(rem % 4096);
  const int l = (int)(rem / 4096);
  const int j = rp >> 2, g = rp & 3;
  out[idx] = f2bf(in[((size_t)l * 4096 + g * 1024 + j) * Kin + col0 + k]);
}

__global__ __launch_bounds__(256) void nmt_convplain(
    const float* __restrict__ in, ushort* __restrict__ out, size_t n)
{
  const size_t idx = (size_t)blockIdx.x * 256 + threadIdx.x;
  if (idx < n) out[idx] = f2bf(in[idx]);
}

__global__ __launch_bounds__(256) void nmt_bias(
    const float* __restrict__ bih, const float* __restrict__ bhh, float* __restrict__ bc)
{
  const int idx = blockIdx.x * 256 + threadIdx.x;
  if (idx >= 4 * 4096) return;
  const int rp = idx & 4095, l = idx >> 12;
  const int j = rp >> 2, g = rp & 3;
  bc[idx] = bih[l * 4096 + g * 1024 + j] + bhh[l * 4096 + g * 1024 + j];
}

__global__ __launch_bounds__(256) void nmt_gather(
    const int* __restrict__ tok, const float* __restrict__ emb,
    ushort* __restrict__ out, int rows)
{
  const size_t idx = (size_t)blockIdx.x * 256 + threadIdx.x;
  if (idx >= (size_t)rows * 512) return;
  const int k = (int)(idx & 511);
  const int r = (int)(idx >> 9);
  out[idx] = f2bf(emb[(size_t)tok[r] * 512 + k]);
}

__global__ __launch_bounds__(256) void nmt_pre(
    const ushort* __restrict__ A, const ushort* __restrict__ Wp,
    const float* __restrict__ bc0, float* __restrict__ out, int K)
{
  __shared__ __align__(16) char smem[SMEM_BYTES];
  const int m0 = blockIdx.x * 64, n0 = blockIdx.y * 64;
  const int lane = threadIdx.x & 63;
  const int cb = lane & 15;
  f32x4 acc[4];
#pragma unroll
  for (int nf = 0; nf < 4; ++nf) {
    const float bv = bc0[n0 + nf * 16 + cb];
#pragma unroll
    for (int r = 0; r < 4; ++r) acc[nf][r] = bv;
  }
  gemm_term(A, K, Wp, K, K, m0, n0, acc, smem);
  store_f32(out, 4096, m0, n0, acc);
}

__global__ __launch_bounds__(256) void nmt_decinit(
    const ushort* __restrict__ henc, float* c, ushort* h)
{
  const int idx = blockIdx.x * 256 + threadIdx.x;
  if (idx >= 65536) return;
  const ushort hv = henc[((size_t)3 * 49 + 48) * 65536 + idx];
  const float cv = c[3 * 65536 + idx];
  c[idx] = cv; c[65536 + idx] = cv; c[2 * 65536 + idx] = cv;
  h[idx] = hv; h[65536 + idx] = hv; h[2 * 65536 + idx] = hv; h[3 * 65536 + idx] = hv;
}

// SV precompute: SV[b][s][:] = senc[b][s][:] @ attW2^T  (rows s<48 stored)
__global__ __launch_bounds__(256) void nmt_sv(
    const ushort* __restrict__ senc, const ushort* __restrict__ attW,
    ushort* __restrict__ SV)
{
  __shared__ __align__(16) char smem[SMEM_BYTES];
  const int b = blockIdx.x;
  const int n0 = blockIdx.y * 64;
  const int tid = threadIdx.x, lane = tid & 63, w = tid >> 6;
  const int rbase = w * 16 + ((lane >> 4) << 2), cb = lane & 15;
  f32x4 acc[4];
#pragma unroll
  for (int nf = 0; nf < 4; ++nf)
#pragma unroll
    for (int r = 0; r < 4; ++r) acc[nf][r] = 0.f;
  gemm_term(senc + (size_t)b * 49152, 1024, attW + 1024, 2048, 1024, 0, n0,
            acc, smem);
#pragma unroll
  for (int nf = 0; nf < 4; ++nf)
#pragma unroll
    for (int r = 0; r < 4; ++r) {
      const int row = rbase + r;
      if (row < 48)
        SV[(size_t)b * 49152 + row * 1024 + n0 + nf * 16 + cb] = f2bf(acc[nf][r]);
    }
}

// ---------------------------------------------------------------------------
// Encoder skewed wavefront tick (R13): cell (l, t=v-2l) uses look-ahead
// partial pbufE[l] (bias + Wih_l*h_{l-1}(t), computed at tick v-1); partial
// role computes pbufE[l] for tick v+1 (t' = v+1-2l).
// Grid (64, ncell + npart): y<ncell -> cell l=lc0+y; else partial l=lp0+y-ncell.
// ---------------------------------------------------------------------------
__global__ __launch_bounds__(256) void nmt_enc_tick(
    int v, int lc0, int ncell, int lp0,
    ushort* __restrict__ henc, ushort* __restrict__ srcenc,
    float* __restrict__ c,
    const ushort* __restrict__ WihR, const ushort* __restrict__ Whh,
    const float* __restrict__ X0, const float* __restrict__ bcE,
    float* __restrict__ pbufE)
{
  __shared__ __align__(16) char smem[SMEM_BYTES];
  const int n0 = blockIdx.x * 64;
  const int tid = threadIdx.x, lane = tid & 63, w = tid >> 6;
  const int rbase = w * 16 + ((lane >> 4) << 2), cb = lane & 15;
  f32x4 acc[4];
  if ((int)blockIdx.y < ncell) {
    const int l = lc0 + blockIdx.y;
    const int t = v - 2 * l;
    if (l == 0) {
#pragma unroll
      for (int nf = 0; nf < 4; ++nf)
#pragma unroll
        for (int r = 0; r < 4; ++r)
          acc[nf][r] = X0[(size_t)t * 262144 + (size_t)(rbase + r) * 4096 + n0 + nf * 16 + cb];
    } else {
#pragma unroll
      for (int nf = 0; nf < 4; ++nf)
#pragma unroll
        for (int r = 0; r < 4; ++r)
          acc[nf][r] = pbufE[(size_t)l * 262144 + (size_t)(rbase + r) * 4096 + n0 + nf * 16 + cb];
    }
    gemm_term(henc + ((size_t)l * 49 + t) * 65536, 1024,
              Whh + (size_t)l * 4194304, 1024, 1024, 0, n0, acc, smem);
    cell_store((float*)smem, acc, c + l * 65536,
               henc + ((size_t)l * 49 + t + 1) * 65536,
               (l == 3) ? (srcenc + t * 1024) : (ushort*)nullptr, n0 >> 2);
  } else {
    const int l = lp0 + (blockIdx.y - ncell);   // 1..3
    const int tp = v + 1 - 2 * l;
#pragma unroll
    for (int nf = 0; nf < 4; ++nf) {
      const float bv = bcE[l * 4096 + n0 + nf * 16 + cb];
#pragma unroll
      for (int r = 0; r < 4; ++r) acc[nf][r] = bv;
    }
    gemm_term(henc + ((size_t)(l - 1) * 49 + tp + 1) * 65536, 1024,
              WihR + (size_t)(l - 1) * 4194304, 1024, 1024, 0, n0, acc, smem);
    store_f32(pbufE + (size_t)l * 262144, 4096, 0, n0, acc);
  }
}

// ---------------------------------------------------------------------------
// Decoder stage l (grid 64 x 2), R7/R15 structure.
// ---------------------------------------------------------------------------
__global__ __launch_bounds__(256) void nmt_dec_stage(
    int l, const ushort* __restrict__ hp, ushort* __restrict__ hn,
    float* __restrict__ c,
    const ushort* __restrict__ Whh, const ushort* __restrict__ WihR,
    const ushort* __restrict__ Wd0a, const ushort* __restrict__ attbf,
    const float* __restrict__ Y0t, const float* __restrict__ bcD,
    float* __restrict__ pbuf)
{
  __shared__ __align__(16) char smem[SMEM_BYTES];
  const int n0 = blockIdx.x * 64;
  const int tid = threadIdx.x, lane = tid & 63, w = tid >> 6;
  const int rbase = w * 16 + ((lane >> 4) << 2), cb = lane & 15;
  f32x4 acc[4];
  if (blockIdx.y == 0) {
    if (l == 0) {
#pragma unroll
      for (int nf = 0; nf < 4; ++nf)
#pragma unroll
        for (int r = 0; r < 4; ++r) {
          const size_t o = (size_t)(rbase + r) * 4096 + n0 + nf * 16 + cb;
          acc[nf][r] = Y0t[o] + pbuf[o];
        }
      gemm_term(attbf, 1024, Wd0a, 1024, 1024, 0, n0, acc, smem);
    } else {
#pragma unroll
      for (int nf = 0; nf < 4; ++nf)
#pragma unroll
        for (int r = 0; r < 4; ++r)
          acc[nf][r] = pbuf[(size_t)l * 262144 + (size_t)(rbase + r) * 4096 + n0 + nf * 16 + cb];
      gemm_term(hn + (l - 1) * 65536, 1024, WihR + (size_t)(l - 1) * 4194304,
                1024, 1024, 0, n0, acc, smem);
    }
    cell_store((float*)smem, acc, c + l * 65536, hn + l * 65536,
               (ushort*)nullptr, n0 >> 2);
  } else {
    const int lp = (l + 1) & 3;
    if (lp == 0) {
#pragma unroll
      for (int nf = 0; nf < 4; ++nf)
#pragma unroll
        for (int r = 0; r < 4; ++r) acc[nf][r] = 0.f;
      gemm_term(hn, 1024, Whh, 1024, 1024, 0, n0, acc, smem);
    } else {
#pragma unroll
      for (int nf = 0; nf < 4; ++nf) {
        const float bv = bcD[lp * 4096 + n0 + nf * 16 + cb];
#pragma unroll
        for (int r = 0; r < 4; ++r) acc[nf][r] = bv;
      }
      gemm_term(hp + lp * 65536, 1024, Whh + (size_t)lp * 4194304,
                1024, 1024, 0, n0, acc, smem);
    }
    store_f32(pbuf + (size_t)lp * 262144, 4096, 0, n0, acc);
  }
}

// one-off: pbuf0 = Whh0 * h0(init) before step 0
__global__ __launch_bounds__(256) void nmt_partial0(
    const ushort* __restrict__ h0, const ushort* __restrict__ Whh0,
    float* __restrict__ pbuf)
{
  __shared__ __align__(16) char smem[SMEM_BYTES];
  const int n0 = blockIdx.x * 64;
  f32x4 acc[4];
#pragma unroll
  for (int nf = 0; nf < 4; ++nf)
#pragma unroll
    for (int r = 0; r < 4; ++r) acc[nf][r] = 0.f;
  gemm_term(h0, 1024, Whh0, 1024, 1024, 0, n0, acc, smem);
  store_f32(pbuf, 4096, 0, n0, acc);
}

// Stage A: blocks 0..63 attnA (scores/softmax/ctx2); blocks 64..79 HB gemm.
__global__ __launch_bounds__(256) void nmt_attnAB(
    const ushort* __restrict__ h3, const ushort* __restrict__ senc,
    const ushort* __restrict__ SV, const ushort* __restrict__ attW,
    float* __restrict__ ctx2, float* __restrict__ hb)
{
  __shared__ __align__(16) char smem[SMEM_BYTES];
  const int bid = blockIdx.x;
  const int tid = threadIdx.x, lane = tid & 63, w = tid >> 6;
  if (bid < 64) {
    float* sc = (float*)smem;
    float* al = (float*)smem + 64;
    const int b = bid;
    const ushort* sb = senc + (size_t)b * 49152;
    const ushort* vb = SV + (size_t)b * 49152;
    float hreg[16];
#pragma unroll
    for (int q = 0; q < 16; ++q) hreg[q] = bf2f(h3[b * 1024 + lane * 16 + q]);
    for (int s = w; s < 48; s += 4) {
      const ushort* vr = sb + s * 1024 + lane * 16;
      float p = 0.f;
#pragma unroll
      for (int q = 0; q < 16; ++q) p += bf2f(vr[q]) * hreg[q];
      for (int d = 1; d < 64; d <<= 1) p += __shfl_xor(p, d);
      if (lane == 0) sc[s] = p;
    }
    __syncthreads();
    if (tid < 64) {
      const float v = (lane < 48) ? sc[lane] : -3.4e38f;
      float m = v;
      for (int d = 1; d < 64; d <<= 1) m = fmaxf(m, __shfl_xor(m, d));
      float e = (lane < 48) ? expf(v - m) : 0.f;
      float s = e;
      for (int d = 1; d < 64; d <<= 1) s += __shfl_xor(s, d);
      al[lane] = e / s;
    }
    __syncthreads();
    const int k0 = tid * 4;
    float a0 = 0, a1 = 0, a2 = 0, a3 = 0;
    for (int s = 0; s < 48; ++s) {
      const float als = al[s];
      const ushort* vr = vb + s * 1024 + k0;
      a0 += als * bf2f(vr[0]); a1 += als * bf2f(vr[1]);
      a2 += als * bf2f(vr[2]); a3 += als * bf2f(vr[3]);
    }
    ctx2[b * 1024 + k0 + 0] = a0; ctx2[b * 1024 + k0 + 1] = a1;
    ctx2[b * 1024 + k0 + 2] = a2; ctx2[b * 1024 + k0 + 3] = a3;
  } else {
    const int n0 = (bid - 64) * 64;
    f32x4 acc[4];
#pragma unroll
    for (int nf = 0; nf < 4; ++nf)
#pragma unroll
      for (int r = 0; r < 4; ++r) acc[nf][r] = 0.f;
    gemm_term(h3, 1024, attW, 2048, 1024, 0, n0, acc, smem);
    store_f32(hb, 1024, 0, n0, acc);
  }
}

// Stage B: att = tanh(hb + ctx2) -> attbf (feedback) + attves[t]
__global__ __launch_bounds__(256) void nmt_attnSB(
    const float* __restrict__ ctx2, const float* __restrict__ hb,
    ushort* __restrict__ attbf, ushort* __restrict__ av_t)
{
  const int base = blockIdx.x * 1024 + threadIdx.x * 4;
#pragma unroll
  for (int k = 0; k < 4; ++k) {
    const int i = base + k;
    const ushort us = f2bf(tanhf_fast(hb[i] + ctx2[i]));
    attbf[i] = us;
    av_t[i] = us;
  }
}

// ---------------------------------------------------------------------------
// Readout v4 (R15): M-tile 2, depth-2 pipelined light-sync rounds.
// Grid (24 m-groups, 500 n-tiles). LDS 48KB: 2 slots x {A0,A1,B} x 8KB.
// ---------------------------------------------------------------------------
__global__ __launch_bounds__(256) void nmt_readout(
    const ushort* __restrict__ attves, const ushort* __restrict__ routW,
    const int* __restrict__ tgt, float* __restrict__ pmax,
    float* __restrict__ psum, float* __restrict__ goldl)
{
  __shared__ __align__(16) char smem[SMEM_RO];
  const int g = blockIdx.x;
  const int n0 = blockIdx.y * 64;
  const int tid = threadIdx.x, lane = tid & 63, w = tid >> 6;
  const int rbase = w * 16 + ((lane >> 4) << 2), cb = lane & 15;
  const int r0 = tid >> 3;
  const int cge = (tid & 7) << 3;
  const int soX = r0 * 128 + (((tid & 7) << 4) ^ ((r0 & 7) << 4));
  const int axor = (lane & 7) << 4;
  const int arow = (w * 16 + (lane & 15)) * 128;
  const int brow = (lane & 15) * 128;
  const int kb0 = (lane >> 4) << 4;

  const ushort* A0r0 = attves + (size_t)(g * 128 + r0) * 1024 + cge;
  const ushort* A0r1 = attves + (size_t)(g * 128 + r0 + 32) * 1024 + cge;
  const ushort* A1r0 = attves + (size_t)(g * 128 + 64 + r0) * 1024 + cge;
  const ushort* A1r1 = attves + (size_t)(g * 128 + 64 + r0 + 32) * 1024 + cge;
  const ushort* Br0  = routW + (size_t)(n0 + r0) * 1024 + cge;
  const ushort* Br1  = routW + (size_t)(n0 + r0 + 32) * 1024 + cge;

  f32x4 acc[2][4];
#pragma unroll
  for (int mi = 0; mi < 2; ++mi)
#pragma unroll
    for (int nf = 0; nf < 4; ++nf)
#pragma unroll
      for (int r = 0; r < 4; ++r) acc[mi][nf][r] = 0.f;

  uint4 ra0 = *(const uint4*)(A0r0);
  uint4 ra1 = *(const uint4*)(A0r1);
  uint4 ra2 = *(const uint4*)(A1r0);
  uint4 ra3 = *(const uint4*)(A1r1);
  uint4 rb0 = *(const uint4*)(Br0);
  uint4 rb1 = *(const uint4*)(Br1);
  {
    char* sl = smem;
    *(uint4*)(sl + soX) = ra0;          *(uint4*)(sl + 4096 + soX) = ra1;
    *(uint4*)(sl + 8192 + soX) = ra2;   *(uint4*)(sl + 12288 + soX) = ra3;
    *(uint4*)(sl + 16384 + soX) = rb0;  *(uint4*)(sl + 20480 + soX) = rb1;
  }
  ra0 = *(const uint4*)(A0r0 + 64);
  ra1 = *(const uint4*)(A0r1 + 64);
  ra2 = *(const uint4*)(A1r0 + 64);
  ra3 = *(const uint4*)(A1r1 + 64);
  rb0 = *(const uint4*)(Br0 + 64);
  rb1 = *(const uint4*)(Br1 + 64);

  for (int kt = 0; kt < 1024; kt += 64) {
    NMT_SYNC_LIGHT();
    if (kt + 64 < 1024) {
      char* sl = smem + ((((kt >> 6) + 1) & 1) ? 24576 : 0);
      *(uint4*)(sl + soX) = ra0;          *(uint4*)(sl + 4096 + soX) = ra1;
      *(uint4*)(sl + 8192 + soX) = ra2;   *(uint4*)(sl + 12288 + soX) = ra3;
      *(uint4*)(sl + 16384 + soX) = rb0;  *(uint4*)(sl + 20480 + soX) = rb1;
      if (kt + 128 < 1024) {
        ra0 = *(const uint4*)(A0r0 + kt + 128);
        ra1 = *(const uint4*)(A0r1 + kt + 128);
        ra2 = *(const uint4*)(A1r0 + kt + 128);
        ra3 = *(const uint4*)(A1r1 + kt + 128);
        rb0 = *(const uint4*)(Br0 + kt + 128);
        rb1 = *(const uint4*)(Br1 + kt + 128);
      }
    }
    char* cur = smem + (((kt >> 6) & 1) ? 24576 : 0);
#pragma unroll
    for (int ks = 0; ks < 2; ++ks) {
      const int kb = (ks << 6) + kb0;
      bf16x8 bf0 = *(const bf16x8*)(cur + 16384 + 0 * 2048 + brow + (kb ^ axor));
      bf16x8 bf1 = *(const bf16x8*)(cur + 16384 + 1 * 2048 + brow + (kb ^ axor));
      bf16x8 bf2 = *(const bf16x8*)(cur + 16384 + 2 * 2048 + brow + (kb ^ axor));
      bf16x8 bf3 = *(const bf16x8*)(cur + 16384 + 3 * 2048 + brow + (kb ^ axor));
      bf16x8 af0 = *(const bf16x8*)(cur + arow + (kb ^ axor));
      bf16x8 af1 = *(const bf16x8*)(cur + 8192 + arow + (kb ^ axor));
      acc[0][0] = __builtin_amdgcn_mfma_f32_16x16x32_bf16(af0, bf0, acc[0][0], 0, 0, 0);
      acc[0][1] = __builtin_amdgcn_mfma_f32_16x16x32_bf16(af0, bf1, acc[0][1], 0, 0, 0);
      acc[0][2] = __builtin_amdgcn_mfma_f32_16x16x32_bf16(af0, bf2, acc[0][2], 0, 0, 0);
      acc[0][3] = __builtin_amdgcn_mfma_f32_16x16x32_bf16(af0, bf3, acc[0][3], 0, 0, 0);
      acc[1][0] = __builtin_amdgcn_mfma_f32_16x16x32_bf16(af1, bf0, acc[1][0], 0, 0, 0);
      acc[1][1] = __builtin_amdgcn_mfma_f32_16x16x32_bf16(af1, bf1, acc[1][1], 0, 0, 0);
      acc[1][2] = __builtin_amdgcn_mfma_f32_16x16x32_bf16(af1, bf2, acc[1][2], 0, 0, 0);
      acc[1][3] = __builtin_amdgcn_mfma_f32_16x16x32_bf16(af1, bf3, acc[1][3], 0, 0, 0);
    }
  }

#pragma unroll
  for (int mi = 0; mi < 2; ++mi) {
    const int gm = g * 2 + mi;
    if (gm >= 47) continue;
#pragma unroll
    for (int r = 0; r < 4; ++r) {
      float lm = fmaxf(fmaxf(acc[mi][0][r], acc[mi][1][r]),
                       fmaxf(acc[mi][2][r], acc[mi][3][r]));
      for (int d = 1; d < 16; d <<= 1) lm = fmaxf(lm, __shfl_xor(lm, d));
      float ls = 0.f;
#pragma unroll
      for (int nf = 0; nf < 4; ++nf) ls += expf(acc[mi][nf][r] - lm);
      for (int d = 1; d < 16; d <<= 1) ls += __shfl_xor(ls, d);
      const int grow = gm * 64 + rbase + r;
      if (cb == 0) {
        pmax[(size_t)grow * 500 + blockIdx.y] = lm;
        psum[(size_t)grow * 500 + blockIdx.y] = ls;
      }
      const int t = grow >> 6, b = grow & 63;
      const int gold = tgt[(t + 1) * 64 + b];
#pragma unroll
      for (int nf = 0; nf < 4; ++nf)
        if (n0 + nf * 16 + cb == gold) goldl[grow] = acc[mi][nf][r];
    }
  }
}

__global__ __launch_bounds__(64) void nmt_combine(
    const float* __restrict__ pmax, const float* __restrict__ psum,
    const float* __restrict__ goldl, const int* __restrict__ tgt,
    float* __restrict__ lpm)
{
  const int row = blockIdx.x;
  const int lane = threadIdx.x;
  float m = -3.4e38f, s = 0.f;
  for (int i = lane; i < 500; i += 64) {
    const float pm = pmax[(size_t)row * 500 + i];
    const float ps = psum[(size_t)row * 500 + i];
    if (pm > m) { s = s * expf(m - pm) + ps; m = pm; }
    else        { s += ps * expf(pm - m); }
  }
  for (int d = 1; d < 64; d <<= 1) {
    const float om = __shfl_xor(m, d), os = __shfl_xor(s, d);
    if (om > m) { s = s * expf(m - om) + os; m = om; }
    else        { s += os * expf(om - m); }
  }
  if (lane == 0) {
    const int t = row >> 6, b = row & 63;
    const int gold = tgt[(t + 1) * 64 + b];
    const float lp = goldl[row] - m - logf(s);
    lpm[row] = (gold != 0) ? lp : 0.f;
  }
}

__global__ __launch_bounds__(64) void nmt_final(
    const float* __restrict__ lpm, float* __restrict__ out)
{
  const int b = threadIdx.x;
  float s = 0.f;
  for (int t = 0; t < 47; ++t) s += lpm[t * 64 + b];
  out[b] = s;
}

// ===========================================================================
extern "C" void kernel_launch(void* const* d_in, const int* in_sizes, int n_in,
                              void* d_out, int out_size, void* d_ws, size_t ws_size,
                              hipStream_t stream)
{
  (void)in_sizes; (void)n_in; (void)out_size; (void)ws_size;
  const int*   src_tok  = (const int*)d_in[0];
  const int*   tgt_tok  = (const int*)d_in[1];
  const float* src_emb  = (const float*)d_in[2];
  const float* tgt_emb  = (const float*)d_in[3];
  const float* eWih0    = (const float*)d_in[4];
  const float* eWihR    = (const float*)d_in[5];
  const float* eWhh     = (const float*)d_in[6];
  const float* ebih     = (const float*)d_in[7];
  const float* ebhh     = (const float*)d_in[8];
  const float* dWih0    = (const float*)d_in[9];
  const float* dWihR    = (const float*)d_in[10];
  const float* dWhh     = (const float*)d_in[11];
  const float* dbih     = (const float*)d_in[12];
  const float* dbhh     = (const float*)d_in[13];
  const float* attW_f   = (const float*)d_in[14];
  const float* routW_f  = (const float*)d_in[15];

  // ---- workspace carve (deterministic) ----
  char* p = (char*)d_ws;
  auto alloc = [&](size_t bytes) { void* r = (void*)p; p += (bytes + 255) & ~(size_t)255; return r; };
  ushort* eWih0p = (ushort*)alloc((size_t)4096 * 512 * 2);
  ushort* eWihRp = (ushort*)alloc((size_t)3 * 4096 * 1024 * 2);
  ushort* eWhhp  = (ushort*)alloc((size_t)4 * 4096 * 1024 * 2);
  ushort* dWih0y = (ushort*)alloc((size_t)4096 * 512 * 2);
  ushort* dWih0a = (ushort*)alloc((size_t)4096 * 1024 * 2);
  ushort* dWihRp = (ushort*)alloc((size_t)3 * 4096 * 1024 * 2);
  ushort* dWhhp  = (ushort*)alloc((size_t)4 * 4096 * 1024 * 2);
  ushort* attWb  = (ushort*)alloc((size_t)1024 * 2048 * 2);
  ushort* routWb = (ushort*)alloc((size_t)32000 * 1024 * 2);
  ushort* srcx   = (ushort*)alloc((size_t)3072 * 512 * 2);
  ushort* tgtx   = (ushort*)alloc((size_t)3008 * 512 * 2);
  ushort* henc   = (ushort*)alloc((size_t)4 * 49 * 65536 * 2);
  ushort* hA     = (ushort*)alloc((size_t)4 * 65536 * 2);
  ushort* hB     = (ushort*)alloc((size_t)4 * 65536 * 2);
  ushort* srcenc = (ushort*)alloc((size_t)64 * 49152 * 2);
  ushort* SVbuf  = (ushort*)alloc((size_t)64 * 49152 * 2);
  ushort* attbf  = (ushort*)alloc((size_t)65536 * 2);
  ushort* attves = (ushort*)alloc((size_t)3072 * 1024 * 2);   // padded rows
  float*  ctx2   = (float*)alloc((size_t)65536 * 4);
  float*  hbuf   = (float*)alloc((size_t)65536 * 4);
  float*  pbuf   = (float*)alloc((size_t)4 * 262144 * 4);
  float*  pbufE  = (float*)alloc((size_t)4 * 262144 * 4);
  float*  X0     = (float*)alloc((size_t)3072 * 4096 * 4);
  float*  Y0     = (float*)alloc((size_t)3008 * 4096 * 4);
  float*  bcE    = (float*)alloc((size_t)16384 * 4);
  float*  bcD    = (float*)alloc((size_t)16384 * 4);
  float*  cbuf   = (float*)alloc((size_t)4 * 65536 * 4);
  float*  pmaxb  = (float*)alloc((size_t)3008 * 500 * 4);
  float*  psumb  = (float*)alloc((size_t)3008 * 500 * 4);
  float*  goldl  = (float*)alloc((size_t)3008 * 4);
  float*  lpm    = (float*)alloc((size_t)3008 * 4);

  const dim3 B256(256);
  auto g1 = [](size_t n) { return dim3((unsigned)((n + 255) / 256)); };

  nmt_init<<<g1(262144), B256, 0, stream>>>(cbuf, henc, attbf);

  nmt_convperm<<<g1((size_t)4096 * 512), B256, 0, stream>>>(eWih0, eWih0p, 1, 512, 0, 512);
  nmt_convperm<<<g1((size_t)3 * 4096 * 1024), B256, 0, stream>>>(eWihR, eWihRp, 3, 1024, 0, 1024);
  nmt_convperm<<<g1((size_t)4 * 4096 * 1024), B256, 0, stream>>>(eWhh, eWhhp, 4, 1024, 0, 1024);
  nmt_convperm<<<g1((size_t)4096 * 512), B256, 0, stream>>>(dWih0, dWih0y, 1, 1536, 0, 512);
  nmt_convperm<<<g1((size_t)4096 * 1024), B256, 0, stream>>>(dWih0, dWih0a, 1, 1536, 512, 1024);
  nmt_convperm<<<g1((size_t)3 * 4096 * 1024), B256, 0, stream>>>(dWihR, dWihRp, 3, 1024, 0, 1024);
  nmt_convperm<<<g1((size_t)4 * 4096 * 1024), B256, 0, stream>>>(dWhh, dWhhp, 4, 1024, 0, 1024);
  nmt_convplain<<<g1((size_t)1024 * 2048), B256, 0, stream>>>(attW_f, attWb, (size_t)1024 * 2048);
  nmt_convplain<<<g1((size_t)32000 * 1024), B256, 0, stream>>>(routW_f, routWb, (size_t)32000 * 1024);
  nmt_bias<<<g1(16384), B256, 0, stream>>>(ebih, ebhh, bcE);
  nmt_bias<<<g1(16384), B256, 0, stream>>>(dbih, dbhh, bcD);
  nmt_gather<<<g1((size_t)3072 * 512), B256, 0, stream>>>(src_tok, src_emb, srcx, 3072);
  nmt_gather<<<g1((size_t)3008 * 512), B256, 0, stream>>>(tgt_tok, tgt_emb, tgtx, 3008);

  nmt_pre<<<dim3(48, 64), B256, 0, stream>>>(srcx, eWih0p, bcE, X0, 512);
  nmt_pre<<<dim3(47, 64), B256, 0, stream>>>(tgtx, dWih0y, bcD, Y0, 512);

  // ---- encoder skewed wavefront: tick v = cells (l, v-2l) + partials ----
  for (int v = 0; v < 54; ++v) {
    int lc0 = (v > 47) ? ((v - 47 + 1) / 2) : 0;
    int lc1 = (v / 2 < 3) ? (v / 2) : 3;
    int ncell = lc1 - lc0 + 1;
    int lp0 = (v + 1 > 47) ? ((v + 1 - 47 + 1) / 2) : 1;
    if (lp0 < 1) lp0 = 1;
    int lp1 = ((v + 1) / 2 < 3) ? ((v + 1) / 2) : 3;
    int npart = (lp1 >= lp0) ? (lp1 - lp0 + 1) : 0;
    nmt_enc_tick<<<dim3(64, ncell + npart), B256, 0, stream>>>(
        v, lc0, ncell, lp0, henc, srcenc, cbuf, eWihRp, eWhhp, X0, bcE, pbufE);
  }
  nmt_decinit<<<g1(65536), B256, 0, stream>>>(henc, cbuf, hA);
  nmt_sv<<<dim3(64, 16), B256, 0, stream>>>(srcenc, attWb, SVbuf);
  nmt_partial0<<<dim3(64), B256, 0, stream>>>(hA, dWhhp, pbuf);

  // ---- decoder scan: per step 4 stage launches + attn (A,B) [R15] ----
  for (int t = 0; t < 47; ++t) {
    ushort* hp = (t & 1) ? hB : hA;
    ushort* hn = (t & 1) ? hA : hB;
    for (int l = 0; l < 4; ++l) {
      nmt_dec_stage<<<dim3(64, 2), B256, 0, stream>>>(
          l, hp, hn, cbuf, dWhhp, dWihRp, dWih0a, attbf,
          Y0 + (size_t)t * 262144, bcD, pbuf);
    }
    nmt_attnAB<<<dim3(80), B256, 0, stream>>>(hn + 3 * 65536, srcenc, SVbuf,
                                              attWb, ctx2, hbuf);
    nmt_attnSB<<<dim3(64), B256, 0, stream>>>(ctx2, hbuf, attbf,
                                              attves + (size_t)t * 65536);
  }

  // ---- readout (pipelined, M-tile 2) + log-softmax + masked gold sum ----
  nmt_readout<<<dim3(24, 500), B256, 0, stream>>>(attves, routWb, tgt_tok,
                                                  pmaxb, psumb, goldl);
  nmt_combine<<<dim3(3008), dim3(64), 0, stream>>>(pmaxb, psumb, goldl, tgt_tok, lpm);
  nmt_final<<<dim3(1), dim3(64), 0, stream>>>(lpm, (float*)d_out);
}